// Round 3
// baseline (132.288 us; speedup 1.0000x reference)
//
#include <hip/hip_runtime.h>
#include <hip/hip_cooperative_groups.h>
#include <math.h>

namespace cg = cooperative_groups;

#define BB    8
#define NN    4096
#define DIRS  2
#define TPB   256
#define Q     16                // queries per thread (register-resident)
#define RSIZE 128               // refs per block (LDS-staged)
#define RC    (NN / RSIZE)      // 32 ref chunks
#define CDN   (DIRS * BB * NN)  // 65536 query slots (both directions)
#define NBLK  (RC * DIRS * BB)  // 512 blocks = 2 blocks/CU (co-resident)

// Single cooperative kernel:
//   phase 1: chamfer partial mins per ref-chunk (deterministic stores to ws)
//   grid.sync()
//   phase 2: min-combine over RC partials + EMD + block reduce + atomicAdd(out)
// Clamp note: max(.,0) commutes with min, so clamping partials is exact.
__global__ __launch_bounds__(TPB) void fused_kernel(
    const float* __restrict__ y_true, const float* __restrict__ y_pred,
    float* __restrict__ part, float* __restrict__ out)
{
    __shared__ float4 refs[RSIZE];
    __shared__ float wsum[TPB / 64];

    const int bid = blockIdx.x;
    const int rc  = bid & (RC - 1);   // 0..31
    const int db  = bid >> 5;         // 0..15  == dir*BB + b
    const int dir = db >> 3;
    const int b   = db & (BB - 1);
    const int t   = threadIdx.x;

    // ---- phase 1: chamfer partial mins ----
    const float2* qbase = (const float2*)(dir == 0 ? y_true : y_pred) + (size_t)b * NN;
    const float2* rbase = (const float2*)(dir == 0 ? y_pred : y_true) + (size_t)b * NN;

    if (t < RSIZE) {
        float2 r = rbase[rc * RSIZE + t];
        refs[t] = make_float4(-2.f * r.x, -2.f * r.y,
                              r.x * r.x + r.y * r.y, 0.f);
    }
    if (bid == 0 && t == 0) out[0] = 0.f;   // init before grid sync
    __syncthreads();

    float qx[Q], qy[Q], m[Q];
    #pragma unroll
    for (int j = 0; j < Q; ++j) {
        float2 qv = qbase[j * TPB + t];      // Q*TPB == NN, coalesced
        qx[j] = qv.x; qy[j] = qv.y; m[j] = INFINITY;
    }

    #pragma unroll 4
    for (int k = 0; k < RSIZE; ++k) {
        float4 r = refs[k];
        #pragma unroll
        for (int j = 0; j < Q; ++j) {
            float d = fmaf(qy[j], r.y, fmaf(qx[j], r.x, r.z));
            m[j] = fminf(m[j], d);
        }
    }

    #pragma unroll
    for (int j = 0; j < Q; ++j) {
        int q = j * TPB + t;
        float v = fmaxf(m[j] + (qx[j] * qx[j] + qy[j] * qy[j]), 0.f);
        // layout: part[rc][db][q]
        part[(size_t)rc * CDN + (size_t)db * NN + q] = v;
    }

    cg::this_grid().sync();

    // ---- phase 2: combine + EMD + global sum ----
    const float cd_scale  = 1.0f / (float)BB;
    const float emd_scale = 1.0f / (2.0f * (float)BB * (float)NN);

    float acc = 0.f;

    // chamfer min-combine: each block owns 128 query slots
    if (t < 128) {
        int i = bid * 128 + t;
        float mv = part[i];
        #pragma unroll
        for (int r = 1; r < RC; ++r)
            mv = fminf(mv, part[(size_t)r * CDN + i]);
        acc += mv * cd_scale;
    }

    // EMD: 32768 float2 elements over 131072 threads
    {
        int gid = bid * TPB + t;
        if (gid < BB * NN) {
            float2 tv = ((const float2*)y_true)[gid];
            float2 pv = ((const float2*)y_pred)[gid];
            float c1 = tv.x - pv.x;
            float c2 = (tv.x + tv.y) - (pv.x + pv.y);
            acc = fmaf(c1 * emd_scale, c1, acc);
            acc = fmaf(c2 * emd_scale, c2, acc);
        }
    }

    #pragma unroll
    for (int off = 32; off > 0; off >>= 1)
        acc += __shfl_down(acc, off, 64);

    const int lane = t & 63, wid = t >> 6;
    if (lane == 0) wsum[wid] = acc;
    __syncthreads();
    if (t == 0) {
        float s = wsum[0] + wsum[1] + wsum[2] + wsum[3];
        atomicAdd(out, s);
    }
}

extern "C" void kernel_launch(void* const* d_in, const int* in_sizes, int n_in,
                              void* d_out, int out_size, void* d_ws, size_t ws_size,
                              hipStream_t stream) {
    const float* y_true = (const float*)d_in[0];
    const float* y_pred = (const float*)d_in[1];
    float* out  = (float*)d_out;
    float* part = (float*)d_ws;   // RC*CDN floats = 8 MiB

    void* args[] = { (void*)&y_true, (void*)&y_pred, (void*)&part, (void*)&out };
    hipLaunchCooperativeKernel((void*)fused_kernel, dim3(NBLK), dim3(TPB),
                               args, 0, stream);
}

// Round 4
// 92.837 us; speedup vs baseline: 1.4250x; 1.4250x over previous
//
#include <hip/hip_runtime.h>
#include <math.h>

#define BB    8
#define NN    4096
#define DIRS  2
#define TPB   256
#define Q     16                // queries per thread (register-resident)
#define RSIZE 64                // refs per block (LDS-staged)
#define RC    (NN / RSIZE)      // 64 ref chunks -> 1024 blocks (4/CU)
#define CDN   (DIRS * BB * NN)  // 65536 query slots (both directions)

// --- Kernel A: chamfer partial mins --------------------------------------
// d2 = |q-r|^2 = q^2 + (r^2 - 2 q.r). Track min over refs of (r^2 - 2 q.r).
// Refs staged 2-at-a-time as float4(-2rx0,-2ry0,-2rx1,-2ry1)+float2(r0^2,r1^2)
// so the compiler can pack the two fma chains into v_pk_fma_f32.
// Clamp folded here: max(.,0) commutes with the min-combine in kernel B.
__global__ __launch_bounds__(TPB, 4) void chamfer_kernel(
    const float* __restrict__ y_true, const float* __restrict__ y_pred,
    float* __restrict__ part, float* __restrict__ out)
{
    __shared__ float4 sxy[RSIZE / 2];
    __shared__ float2 sz [RSIZE / 2];

    const int rc  = blockIdx.x;
    const int dir = blockIdx.y;     // 0: true->pred, 1: pred->true
    const int b   = blockIdx.z;
    const int t   = threadIdx.x;

    const float2* qbase  = (const float2*)(dir == 0 ? y_true : y_pred) + (size_t)b * NN;
    const float4* rbase4 = (const float4*)((dir == 0 ? y_pred : y_true) + (size_t)b * NN * 2);

    if (t < RSIZE / 2) {
        float4 r = rbase4[rc * (RSIZE / 2) + t];   // refs 2t, 2t+1 of chunk
        sxy[t] = make_float4(-2.f * r.x, -2.f * r.y, -2.f * r.z, -2.f * r.w);
        sz [t] = make_float2(r.x * r.x + r.y * r.y, r.z * r.z + r.w * r.w);
    }
    if (rc == 0 && dir == 0 && b == 0 && t == 0) out[0] = 0.f;  // init before B
    __syncthreads();

    float qx[Q], qy[Q], m[Q];
    #pragma unroll
    for (int j = 0; j < Q; ++j) {
        float2 qv = qbase[j * TPB + t];            // Q*TPB == NN, coalesced
        qx[j] = qv.x; qy[j] = qv.y; m[j] = INFINITY;
    }

    #pragma unroll 2
    for (int k = 0; k < RSIZE / 2; ++k) {
        float4 xy = sxy[k];
        float2 z  = sz [k];
        #pragma unroll
        for (int j = 0; j < Q; ++j) {
            float d0 = fmaf(qy[j], xy.y, fmaf(qx[j], xy.x, z.x));
            float d1 = fmaf(qy[j], xy.w, fmaf(qx[j], xy.z, z.y));
            m[j] = fminf(m[j], d0);
            m[j] = fminf(m[j], d1);
        }
    }

    #pragma unroll
    for (int j = 0; j < Q; ++j) {
        int q = j * TPB + t;
        float v = fmaxf(m[j] + fmaf(qx[j], qx[j], qy[j] * qy[j]), 0.f);
        // layout: part[rc][dir*BB+b][q]
        part[(size_t)rc * CDN + ((size_t)dir * BB + b) * NN + q] = v;
    }
}

// --- Kernel B: min-combine + EMD + global sum ----------------------------
__global__ __launch_bounds__(TPB) void reduce_kernel(
    const float* __restrict__ y_true, const float* __restrict__ y_pred,
    const float* __restrict__ part, float* __restrict__ out)
{
    const float cd_scale  = 1.0f / (float)BB;
    const float emd_scale = 1.0f / (2.0f * (float)BB * (float)NN);

    const int i = blockIdx.x * TPB + threadIdx.x;  // [0, CDN)

    float mv = part[i];
    #pragma unroll 16
    for (int r = 1; r < RC; ++r)
        mv = fminf(mv, part[(size_t)r * CDN + i]);
    float acc = mv * cd_scale;

    if (i < BB * NN) {                              // EMD over 32768 float2s
        float2 tv = ((const float2*)y_true)[i];
        float2 pv = ((const float2*)y_pred)[i];
        float c1 = tv.x - pv.x;                     // cumsum[0] diff
        float c2 = c1 + (tv.y - pv.y);              // cumsum[1] diff
        acc = fmaf(c1 * emd_scale, c1, acc);
        acc = fmaf(c2 * emd_scale, c2, acc);
    }

    #pragma unroll
    for (int off = 32; off > 0; off >>= 1)
        acc += __shfl_down(acc, off, 64);

    __shared__ float wsum[TPB / 64];
    const int lane = threadIdx.x & 63, wid = threadIdx.x >> 6;
    if (lane == 0) wsum[wid] = acc;
    __syncthreads();
    if (threadIdx.x == 0) {
        float s = wsum[0] + wsum[1] + wsum[2] + wsum[3];
        atomicAdd(out, s);
    }
}

extern "C" void kernel_launch(void* const* d_in, const int* in_sizes, int n_in,
                              void* d_out, int out_size, void* d_ws, size_t ws_size,
                              hipStream_t stream) {
    const float* y_true = (const float*)d_in[0];
    const float* y_pred = (const float*)d_in[1];
    float* out  = (float*)d_out;
    float* part = (float*)d_ws;   // RC*CDN floats = 16 MiB

    chamfer_kernel<<<dim3(RC, DIRS, BB), TPB, 0, stream>>>(y_true, y_pred, part, out);
    reduce_kernel<<<CDN / TPB, TPB, 0, stream>>>(y_true, y_pred, part, out);
}

// Round 5
// 81.514 us; speedup vs baseline: 1.6229x; 1.1389x over previous
//
#include <hip/hip_runtime.h>
#include <math.h>

#define BB    8
#define NN    4096
#define DIRS  2
#define TPB   256
#define Q     16                // queries per thread (register-resident)
#define RSIZE 128               // refs per block (LDS-staged)
#define RC    (NN / RSIZE)      // 32 ref chunks -> 512 blocks (2/CU)
#define CDN   (DIRS * BB * NN)  // 65536 query slots (both directions)

typedef float v2f __attribute__((ext_vector_type(2)));
typedef float v4f __attribute__((ext_vector_type(4)));

#if __has_builtin(__builtin_elementwise_fma) && __has_builtin(__builtin_elementwise_min)
#define VFMA(a,b,c) __builtin_elementwise_fma(a,b,c)
#define VMIN(a,b)   __builtin_elementwise_min(a,b)
#else
static __device__ inline v2f VFMA(v2f a, v2f b, v2f c) {
    v2f r; r.x = fmaf(a.x,b.x,c.x); r.y = fmaf(a.y,b.y,c.y); return r;
}
static __device__ inline v2f VMIN(v2f a, v2f b) {
    v2f r; r.x = fminf(a.x,b.x); r.y = fminf(a.y,b.y); return r;
}
#endif

// --- Kernel A: chamfer partial mins --------------------------------------
// d2 = |q-r|^2 = q^2 + (r^2 - 2 q.r). Track min over refs of (r^2 - 2 q.r).
// Refs processed in PAIRS via packed fp32 (v_pk_fma_f32): per (query, 2 refs)
// = 2 pk-fma + 2 min = 2 instr/pair (scalar path would be 3/pair).
// LDS layout per ref pair: v4f(-2rx0,-2rx1,-2ry0,-2ry1) + v2f(r0^2,r1^2).
// Clamp folded here: max(.,0) commutes with the min-combine in kernel B.
__global__ __launch_bounds__(TPB) void chamfer_kernel(
    const float* __restrict__ y_true, const float* __restrict__ y_pred,
    float* __restrict__ part, float* __restrict__ out)
{
    __shared__ v4f sxy[RSIZE / 2];   // (-2rx0,-2rx1,-2ry0,-2ry1)
    __shared__ v2f sz [RSIZE / 2];   // (r0^2, r1^2)

    const int rc  = blockIdx.x;
    const int dir = blockIdx.y;     // 0: true->pred, 1: pred->true
    const int b   = blockIdx.z;
    const int t   = threadIdx.x;

    const float2* qbase  = (const float2*)(dir == 0 ? y_true : y_pred) + (size_t)b * NN;
    const float4* rbase4 = (const float4*)((dir == 0 ? y_pred : y_true) + (size_t)b * NN * 2);

    if (t < RSIZE / 2) {
        float4 r = rbase4[rc * (RSIZE / 2) + t];   // points 2t,2t+1: (x0,y0,x1,y1)
        v4f xy; xy.x = -2.f * r.x; xy.y = -2.f * r.z;
                xy.z = -2.f * r.y; xy.w = -2.f * r.w;
        sxy[t] = xy;
        v2f z;  z.x = fmaf(r.x, r.x, r.y * r.y);
                z.y = fmaf(r.z, r.z, r.w * r.w);
        sz[t] = z;
    }
    if (rc == 0 && dir == 0 && b == 0 && t == 0) out[0] = 0.f;  // init before B
    __syncthreads();

    float qx[Q], qy[Q];
    v2f   m2[Q];
    #pragma unroll
    for (int j = 0; j < Q; ++j) {
        float2 qv = qbase[j * TPB + t];            // Q*TPB == NN, coalesced
        qx[j] = qv.x; qy[j] = qv.y;
        m2[j].x = INFINITY; m2[j].y = INFINITY;
    }

    #pragma unroll 2
    for (int k = 0; k < RSIZE / 2; ++k) {
        v4f xy = sxy[k];
        v2f z  = sz [k];
        v2f rx = xy.xy;     // (-2rx0, -2rx1)
        v2f ry = xy.zw;     // (-2ry0, -2ry1)
        #pragma unroll
        for (int j = 0; j < Q; ++j) {
            v2f qxv = (v2f)(qx[j]);                // splat (opsel broadcast)
            v2f qyv = (v2f)(qy[j]);
            v2f d = VFMA(ry, qyv, VFMA(rx, qxv, z));
            m2[j] = VMIN(m2[j], d);
        }
    }

    #pragma unroll
    for (int j = 0; j < Q; ++j) {
        int q = j * TPB + t;
        float m = fminf(m2[j].x, m2[j].y);
        float v = fmaxf(m + fmaf(qx[j], qx[j], qy[j] * qy[j]), 0.f);
        // layout: part[rc][dir*BB+b][q]
        part[(size_t)rc * CDN + ((size_t)dir * BB + b) * NN + q] = v;
    }
}

// --- Kernel B: min-combine + EMD + global sum ----------------------------
__global__ __launch_bounds__(TPB) void reduce_kernel(
    const float* __restrict__ y_true, const float* __restrict__ y_pred,
    const float* __restrict__ part, float* __restrict__ out)
{
    const float cd_scale  = 1.0f / (float)BB;
    const float emd_scale = 1.0f / (2.0f * (float)BB * (float)NN);

    const int i = blockIdx.x * TPB + threadIdx.x;  // [0, CDN)

    float mv = part[i];
    #pragma unroll 8
    for (int r = 1; r < RC; ++r)
        mv = fminf(mv, part[(size_t)r * CDN + i]);
    float acc = mv * cd_scale;

    if (i < BB * NN) {                              // EMD over 32768 float2s
        float2 tv = ((const float2*)y_true)[i];
        float2 pv = ((const float2*)y_pred)[i];
        float c1 = tv.x - pv.x;                     // cumsum[0] diff
        float c2 = c1 + (tv.y - pv.y);              // cumsum[1] diff
        acc = fmaf(c1 * emd_scale, c1, acc);
        acc = fmaf(c2 * emd_scale, c2, acc);
    }

    #pragma unroll
    for (int off = 32; off > 0; off >>= 1)
        acc += __shfl_down(acc, off, 64);

    __shared__ float wsum[TPB / 64];
    const int lane = threadIdx.x & 63, wid = threadIdx.x >> 6;
    if (lane == 0) wsum[wid] = acc;
    __syncthreads();
    if (threadIdx.x == 0) {
        float s = wsum[0] + wsum[1] + wsum[2] + wsum[3];
        atomicAdd(out, s);
    }
}

extern "C" void kernel_launch(void* const* d_in, const int* in_sizes, int n_in,
                              void* d_out, int out_size, void* d_ws, size_t ws_size,
                              hipStream_t stream) {
    const float* y_true = (const float*)d_in[0];
    const float* y_pred = (const float*)d_in[1];
    float* out  = (float*)d_out;
    float* part = (float*)d_ws;   // RC*CDN floats = 8 MiB

    chamfer_kernel<<<dim3(RC, DIRS, BB), TPB, 0, stream>>>(y_true, y_pred, part, out);
    reduce_kernel<<<CDN / TPB, TPB, 0, stream>>>(y_true, y_pred, part, out);
}